// Round 10
// baseline (116.806 us; speedup 1.0000x reference)
//
#include <hip/hip_runtime.h>
#include <hip/hip_bf16.h>

#define D_MODEL 64
#define D_STATE 16
#define IMG     32
#define HW      (IMG*IMG)      // 1024
#define V       9
#define B       4
#define GROUPS  4
#define CPG     (D_MODEL/GROUPS) // 16

typedef float f32x4 __attribute__((ext_vector_type(4)));

// ---------------- Kernel 1: GroupNorm ----------------
__global__ __launch_bounds__(256) void gn_kernel(
    const float* __restrict__ u, const float* __restrict__ gamma,
    const float* __restrict__ beta, float* __restrict__ un)
{
    const int b = blockIdx.x / GROUPS;
    const int g = blockIdx.x % GROUPS;
    const float* base = u + ((size_t)b*D_MODEL + g*CPG) * HW;
    const int NE = CPG * HW; // 16384

    float s = 0.f, s2 = 0.f;
    for (int i = threadIdx.x; i < NE; i += 256) {
        float v = base[i];
        s += v; s2 += v*v;
    }
    for (int off = 32; off; off >>= 1) {
        s  += __shfl_down(s,  off);
        s2 += __shfl_down(s2, off);
    }
    __shared__ float red0[4], red1[4];
    const int wave = threadIdx.x >> 6;
    if ((threadIdx.x & 63) == 0) { red0[wave] = s; red1[wave] = s2; }
    __syncthreads();
    if (threadIdx.x == 0) {
        float a = 0.f, c = 0.f;
        for (int i = 0; i < 4; i++) { a += red0[i]; c += red1[i]; }
        red0[0] = a; red1[0] = c;
    }
    __syncthreads();
    const float mean = red0[0] * (1.f/16384.f);
    const float var  = red1[0] * (1.f/16384.f) - mean*mean;
    const float rstd = rsqrtf(var + 1e-5f);

    for (int i = threadIdx.x; i < NE; i += 256) {
        int c = i >> 10;
        int d = g*CPG + c;
        float v = (base[i] - mean) * rstd;
        un[((size_t)b*D_MODEL + d)*HW + (i & (HW-1))] = v*gamma[d] + beta[d];
    }
}

// ---------------- Kernel 2: circular 3x3 convs, LDS-staged, 4 co / block ----------------
__global__ __launch_bounds__(256) void conv_kernel(
    const float* __restrict__ un,
    const float* __restrict__ w_delta, const float* __restrict__ b_delta,
    const float* __restrict__ w_B, const float* __restrict__ w_C,
    const float* __restrict__ dt_sp,
    float* __restrict__ delta, float* __restrict__ Bv, float* __restrict__ Cv)
{
    const int bx    = blockIdx.x;
    const int strip = bx & 3;
    const int cog   = (bx >> 2) % 24;
    const int b     = bx / 96;
    const int co0   = cog * 4;
    const int row0  = strip * 8;

    __shared__ float xs[16][10][32];
    __shared__ float wl[4][D_MODEL*9];

    for (int i = threadIdx.x; i < 4*D_MODEL*9; i += 256) {
        const int cl = i / (D_MODEL*9);
        const int rest = i % (D_MODEL*9);
        const int co = co0 + cl;
        const float* w = (co < 64) ? (w_delta + (size_t)co*(D_MODEL*9))
                       : (co < 80) ? (w_B + (size_t)(co-64)*(D_MODEL*9))
                                   : (w_C + (size_t)(co-80)*(D_MODEL*9));
        wl[cl][rest] = w[rest];
    }

    const int ly = threadIdx.x >> 5;
    const int ox = threadIdx.x & 31;
    const int oy = row0 + ly;

    const float* x = un + (size_t)b*D_MODEL*HW;
    float a0 = 0.f, a1 = 0.f, a2 = 0.f, a3 = 0.f;

    for (int c = 0; c < 4; c++) {
        __syncthreads();
        for (int i = threadIdx.x; i < 16*10*32; i += 256) {
            const int ci = i / 320;
            const int rr = (i % 320) >> 5;
            const int xx = i & 31;
            const int gy = (row0 - 1 + rr) & 31;
            xs[ci][rr][xx] = x[(size_t)(c*16 + ci)*HW + (gy << 5) + xx];
        }
        __syncthreads();

        #pragma unroll
        for (int ci = 0; ci < 16; ci++) {
            float v[3][3];
            #pragma unroll
            for (int dy = 0; dy < 3; dy++)
                #pragma unroll
                for (int dx = 0; dx < 3; dx++)
                    v[dy][dx] = xs[ci][ly + dy][(ox + dx + 31) & 31];
            const int cig = c*16 + ci;
            const float* w0 = &wl[0][cig*9];
            const float* w1 = &wl[1][cig*9];
            const float* w2 = &wl[2][cig*9];
            const float* w3 = &wl[3][cig*9];
            #pragma unroll
            for (int t = 0; t < 9; t++) {
                const float xv = v[t/3][t%3];
                a0 = fmaf(xv, w0[t], a0);
                a1 = fmaf(xv, w1[t], a1);
                a2 = fmaf(xv, w2[t], a2);
                a3 = fmaf(xv, w3[t], a3);
            }
        }
    }

    const int p = (oy << 5) + ox;
    const float dtsp = dt_sp[0];
    float accs[4] = {a0, a1, a2, a3};
    #pragma unroll
    for (int cl = 0; cl < 4; cl++) {
        const int co = co0 + cl;
        float acc = accs[cl];
        if (co < 64) {
            acc += b_delta[co] + dtsp;
            float sp = (acc > 15.f) ? acc : log1pf(__expf(acc));
            sp = fminf(fmaxf(sp, 1e-4f), 5.f);
            delta[((size_t)b*D_MODEL + co)*HW + p] = sp;
        } else if (co < 80) {
            Bv[((size_t)b*D_STATE + (co-64))*HW + p] = acc;
        } else {
            Cv[((size_t)b*D_STATE + (co-80))*HW + p] = acc;
        }
    }
}

// ---------------- Kernel 3: main fused state update (asm-pipelined, nt reads) ----------------
// Cache-policy inversion experiment: s_prev loads carry `nt` (no MALL allocate
// on miss -> pure HBM stream); s_new stores are PLAIN (allocate -> output set
// can live in MALL across replays, shrinking steady-state writeback).
__device__ __forceinline__ f32x4 asm_load4_nt(const float* __restrict__ base, unsigned voff) {
    f32x4 d;
    asm volatile("global_load_dwordx4 %0, %1, %2 nt"
                 : "=v"(d) : "v"(voff), "s"(base) : "memory");
    return d;
}
__device__ __forceinline__ f32x4 asm_load4(const float* __restrict__ base, unsigned voff) {
    f32x4 d;
    asm volatile("global_load_dwordx4 %0, %1, %2"
                 : "=v"(d) : "v"(voff), "s"(base) : "memory");
    return d;
}

// K(n) = 3*(min(n+4,15)-n) newer loads + min(4,n) newer stores
#define STEP(n, K) do { \
    if ((n) + 4 <= 15) { \
        sp[((n)+4)&15] = asm_load4_nt(sp_u, sp_voff + ((n)+4)*4096u); \
        Bn[((n)+4)&15] = asm_load4(Bv_u, bc_voff + ((n)+4)*4096u); \
        Cn[((n)+4)&15] = asm_load4(Cv_u, bc_voff + ((n)+4)*4096u); \
    } \
    asm volatile("s_waitcnt vmcnt(" #K ")" ::: "memory"); \
    __builtin_amdgcn_sched_barrier(0); \
    { \
        const f32x4 own = sp[(n)]; \
        f32x4 s; \
        if (MODE == 0) { s = own; } \
        else if (MODE == 1) { const float nb = __shfl(own.x, laneR, 64); \
                              s.x = own.y; s.y = own.z; s.z = own.w; s.w = nb; } \
        else { const float nb = __shfl(own.w, laneL, 64); \
               s.x = nb; s.y = own.x; s.z = own.y; s.w = own.z; } \
        const float anr = an_[(n)]; \
        f32x4 ab; \
        ab.x = __expf(dl.x*anr); ab.y = __expf(dl.y*anr); \
        ab.z = __expf(dl.z*anr); ab.w = __expf(dl.w*anr); \
        const f32x4 snv = ab*s + du*Bn[(n)]; \
        *(f32x4*)(sn_p + (n)*HW) = snv; \
        y += snv * Cn[(n)]; \
    } \
} while (0)

template<int MODE>
__device__ __forceinline__ void pipe_body(
    const float* __restrict__ sp_u, unsigned sp_voff,
    const float* __restrict__ Bv_u, const float* __restrict__ Cv_u, unsigned bc_voff,
    float* __restrict__ sn_p,
    const f32x4 dl, const f32x4 du, const float* an_,
    f32x4& y, int laneL, int laneR)
{
    f32x4 sp[16], Bn[16], Cn[16];
    #pragma unroll
    for (int p = 0; p < 4; p++) {
        sp[p] = asm_load4_nt(sp_u, sp_voff + p*4096u);
        Bn[p] = asm_load4(Bv_u, bc_voff + p*4096u);
        Cn[p] = asm_load4(Cv_u, bc_voff + p*4096u);
    }
    STEP(0, 12); STEP(1, 13); STEP(2, 14); STEP(3, 15);
    STEP(4, 16); STEP(5, 16); STEP(6, 16); STEP(7, 16);
    STEP(8, 16); STEP(9, 16); STEP(10, 16); STEP(11, 16);
    STEP(12, 13); STEP(13, 10); STEP(14, 7); STEP(15, 4);
}

__global__ __launch_bounds__(256) void main_kernel(
    const float* __restrict__ sprev, const float* __restrict__ ut,
    const float* __restrict__ delta, const float* __restrict__ Bv,
    const float* __restrict__ Cv, const float* __restrict__ logA,
    const float* __restrict__ Dp, const int* __restrict__ gidx,
    float* __restrict__ ynew, float* __restrict__ snew)
{
    const int blk = blockIdx.x;
    const int d   = blk % D_MODEL;
    const int tmp = blk / D_MODEL;
    const int v   = tmp % V;
    const int b   = tmp / V;

    const int t  = threadIdx.x;
    const int p0 = t * 4;
    const int y0 = p0 >> 5;
    const int x0 = p0 & 31;

    const int gi0 = gidx[v*HW];       // src index of output point 0
    const int ryo = gi0 >> 5;         // row offset: src_y = (y + ryo) & 31
    const int rxo = gi0 & 31;         // col rotation: src_x = (x + rxo) & 31

    const int ys   = (y0 + ryo) & 31;
    const int srcv = (ys << 5) + x0;  // aligned float4 base in source row

    const int lane  = t & 63;
    const int laneL = (lane & ~7) | ((lane + 7) & 7);
    const int laneR = (lane & ~7) | ((lane + 1) & 7);

    const size_t bvd = (((size_t)b*V + v)*D_MODEL + d);
    const float* sp_u = sprev + bvd * D_STATE * HW;   // uniform base
    float* sn_p = snew + bvd * D_STATE * HW + p0;

    const float dpd = Dp[d];
    float an_[D_STATE];
    #pragma unroll
    for (int n = 0; n < D_STATE; n++) an_[n] = -__expf(logA[d*D_STATE + n]);

    const f32x4 dl = *(const f32x4*)(delta + ((size_t)b*D_MODEL + d)*HW + p0);
    const f32x4 uu = *(const f32x4*)(ut    + ((size_t)b*D_MODEL + d)*HW + p0);
    const f32x4 du = dl * uu;
    const float* Bv_u = Bv + (size_t)b*D_STATE*HW;    // uniform base
    const float* Cv_u = Cv + (size_t)b*D_STATE*HW;    // uniform base

    f32x4 y = uu * dpd;

    const unsigned sp_voff = (unsigned)srcv * 4u;
    const unsigned bc_voff = (unsigned)p0 * 4u;

    if (rxo == 0) {
        pipe_body<0>(sp_u, sp_voff, Bv_u, Cv_u, bc_voff, sn_p, dl, du, an_, y, laneL, laneR);
    } else if (rxo == 1) {
        pipe_body<1>(sp_u, sp_voff, Bv_u, Cv_u, bc_voff, sn_p, dl, du, an_, y, laneL, laneR);
    } else if (rxo == 31) {
        pipe_body<2>(sp_u, sp_voff, Bv_u, Cv_u, bc_voff, sn_p, dl, du, an_, y, laneL, laneR);
    } else {
        // general fallback: scalar gather (not expected for V_RANGE=1)
        const int4 src4 = *(const int4*)(gidx + v*HW + p0);
        #pragma unroll
        for (int n = 0; n < D_STATE; n++) {
            const float* sp_n = sp_u + n*HW;
            const f32x4 Bn = *(const f32x4*)(Bv_u + n*HW + p0);
            const f32x4 Cn = *(const f32x4*)(Cv_u + n*HW + p0);
            const float anr = an_[n];
            f32x4 s;
            s.x = sp_n[src4.x]; s.y = sp_n[src4.y];
            s.z = sp_n[src4.z]; s.w = sp_n[src4.w];
            f32x4 ab;
            ab.x = __expf(dl.x * anr);
            ab.y = __expf(dl.y * anr);
            ab.z = __expf(dl.z * anr);
            ab.w = __expf(dl.w * anr);
            const f32x4 sn = ab * s + du * Bn;
            *(f32x4*)(sn_p + n*HW) = sn;
            y += sn * Cn;
        }
    }
    *(f32x4*)(ynew + bvd * HW + p0) = y;
}

extern "C" void kernel_launch(void* const* d_in, const int* in_sizes, int n_in,
                              void* d_out, int out_size, void* d_ws, size_t ws_size,
                              hipStream_t stream)
{
    const float* u_t       = (const float*)d_in[0];
    const float* s_prev    = (const float*)d_in[1];
    const float* gamma     = (const float*)d_in[2];
    const float* beta      = (const float*)d_in[3];
    const float* w_delta   = (const float*)d_in[4];
    const float* b_delta   = (const float*)d_in[5];
    const float* w_B       = (const float*)d_in[6];
    const float* w_C       = (const float*)d_in[7];
    const float* log_A     = (const float*)d_in[8];
    const float* D_param   = (const float*)d_in[9];
    const float* dt_sp     = (const float*)d_in[10];
    const int*   gidx      = (const int*)d_in[11];

    float* ws = (float*)d_ws;
    float* un    = ws;
    float* delta = un    + (size_t)B*D_MODEL*HW;
    float* Bv    = delta + (size_t)B*D_MODEL*HW;
    float* Cv    = Bv    + (size_t)B*D_STATE*HW;

    float* ynew = (float*)d_out;
    float* snew = ynew + (size_t)B*V*D_MODEL*HW;

    gn_kernel<<<B*GROUPS, 256, 0, stream>>>(u_t, gamma, beta, un);
    conv_kernel<<<B*96, 256, 0, stream>>>(un, w_delta, b_delta, w_B, w_C, dt_sp,
                                          delta, Bv, Cv);
    main_kernel<<<B*V*D_MODEL, 256, 0, stream>>>(s_prev, u_t, delta, Bv, Cv,
                                                 log_A, D_param, gidx, ynew, snew);
}

// Round 11
// 103.571 us; speedup vs baseline: 1.1278x; 1.1278x over previous
//
#include <hip/hip_runtime.h>
#include <hip/hip_bf16.h>

#define D_MODEL 64
#define D_STATE 16
#define IMG     32
#define HW      (IMG*IMG)      // 1024
#define V       9
#define B       4
#define GROUPS  4
#define CPG     (D_MODEL/GROUPS) // 16
#define NTILE   2304           // B*V*D_MODEL
#define GRID_MAIN 768          // 3 tiles per block, 3 blocks/CU exactly

typedef float f32x4 __attribute__((ext_vector_type(4)));

// ---------------- Kernel 1: GroupNorm ----------------
__global__ __launch_bounds__(256) void gn_kernel(
    const float* __restrict__ u, const float* __restrict__ gamma,
    const float* __restrict__ beta, float* __restrict__ un)
{
    const int b = blockIdx.x / GROUPS;
    const int g = blockIdx.x % GROUPS;
    const float* base = u + ((size_t)b*D_MODEL + g*CPG) * HW;
    const int NE = CPG * HW; // 16384

    float s = 0.f, s2 = 0.f;
    for (int i = threadIdx.x; i < NE; i += 256) {
        float v = base[i];
        s += v; s2 += v*v;
    }
    for (int off = 32; off; off >>= 1) {
        s  += __shfl_down(s,  off);
        s2 += __shfl_down(s2, off);
    }
    __shared__ float red0[4], red1[4];
    const int wave = threadIdx.x >> 6;
    if ((threadIdx.x & 63) == 0) { red0[wave] = s; red1[wave] = s2; }
    __syncthreads();
    if (threadIdx.x == 0) {
        float a = 0.f, c = 0.f;
        for (int i = 0; i < 4; i++) { a += red0[i]; c += red1[i]; }
        red0[0] = a; red1[0] = c;
    }
    __syncthreads();
    const float mean = red0[0] * (1.f/16384.f);
    const float var  = red1[0] * (1.f/16384.f) - mean*mean;
    const float rstd = rsqrtf(var + 1e-5f);

    for (int i = threadIdx.x; i < NE; i += 256) {
        int c = i >> 10;
        int d = g*CPG + c;
        float v = (base[i] - mean) * rstd;
        un[((size_t)b*D_MODEL + d)*HW + (i & (HW-1))] = v*gamma[d] + beta[d];
    }
}

// ---------------- Kernel 2: circular 3x3 convs, LDS-staged, 4 co / block ----------------
__global__ __launch_bounds__(256) void conv_kernel(
    const float* __restrict__ un,
    const float* __restrict__ w_delta, const float* __restrict__ b_delta,
    const float* __restrict__ w_B, const float* __restrict__ w_C,
    const float* __restrict__ dt_sp,
    float* __restrict__ delta, float* __restrict__ Bv, float* __restrict__ Cv)
{
    const int bx    = blockIdx.x;
    const int strip = bx & 3;
    const int cog   = (bx >> 2) % 24;
    const int b     = bx / 96;
    const int co0   = cog * 4;
    const int row0  = strip * 8;

    __shared__ float xs[16][10][32];
    __shared__ float wl[4][D_MODEL*9];

    for (int i = threadIdx.x; i < 4*D_MODEL*9; i += 256) {
        const int cl = i / (D_MODEL*9);
        const int rest = i % (D_MODEL*9);
        const int co = co0 + cl;
        const float* w = (co < 64) ? (w_delta + (size_t)co*(D_MODEL*9))
                       : (co < 80) ? (w_B + (size_t)(co-64)*(D_MODEL*9))
                                   : (w_C + (size_t)(co-80)*(D_MODEL*9));
        wl[cl][rest] = w[rest];
    }

    const int ly = threadIdx.x >> 5;
    const int ox = threadIdx.x & 31;
    const int oy = row0 + ly;

    const float* x = un + (size_t)b*D_MODEL*HW;
    float a0 = 0.f, a1 = 0.f, a2 = 0.f, a3 = 0.f;

    for (int c = 0; c < 4; c++) {
        __syncthreads();
        for (int i = threadIdx.x; i < 16*10*32; i += 256) {
            const int ci = i / 320;
            const int rr = (i % 320) >> 5;
            const int xx = i & 31;
            const int gy = (row0 - 1 + rr) & 31;
            xs[ci][rr][xx] = x[(size_t)(c*16 + ci)*HW + (gy << 5) + xx];
        }
        __syncthreads();

        #pragma unroll
        for (int ci = 0; ci < 16; ci++) {
            float v[3][3];
            #pragma unroll
            for (int dy = 0; dy < 3; dy++)
                #pragma unroll
                for (int dx = 0; dx < 3; dx++)
                    v[dy][dx] = xs[ci][ly + dy][(ox + dx + 31) & 31];
            const int cig = c*16 + ci;
            const float* w0 = &wl[0][cig*9];
            const float* w1 = &wl[1][cig*9];
            const float* w2 = &wl[2][cig*9];
            const float* w3 = &wl[3][cig*9];
            #pragma unroll
            for (int t = 0; t < 9; t++) {
                const float xv = v[t/3][t%3];
                a0 = fmaf(xv, w0[t], a0);
                a1 = fmaf(xv, w1[t], a1);
                a2 = fmaf(xv, w2[t], a2);
                a3 = fmaf(xv, w3[t], a3);
            }
        }
    }

    const int p = (oy << 5) + ox;
    const float dtsp = dt_sp[0];
    float accs[4] = {a0, a1, a2, a3};
    #pragma unroll
    for (int cl = 0; cl < 4; cl++) {
        const int co = co0 + cl;
        float acc = accs[cl];
        if (co < 64) {
            acc += b_delta[co] + dtsp;
            float sp = (acc > 15.f) ? acc : log1pf(__expf(acc));
            sp = fminf(fmaxf(sp, 1e-4f), 5.f);
            delta[((size_t)b*D_MODEL + co)*HW + p] = sp;
        } else if (co < 80) {
            Bv[((size_t)b*D_STATE + (co-64))*HW + p] = acc;
        } else {
            Cv[((size_t)b*D_STATE + (co-80))*HW + p] = acc;
        }
    }
}

// ---------------- Kernel 3: main fused state update ----------------
// Persistent 3-tile blocks, pipeline continuous across tile boundaries.
// grid = 768 (3 blocks/CU exact); block k: d = k%64 (tile-invariant),
// tiles tau = k + 768*i. During tile steps 13-15, next tile's prologue
// (dl, u, planes 0-2) is issued so VMEM never drains. Counted vmcnt
// throughout (steady 12; boundary 13/14); shift MODE = runtime-uniform select.
__device__ __forceinline__ f32x4 asm_load4(const float* __restrict__ base, unsigned voff) {
    f32x4 d;
    asm volatile("global_load_dwordx4 %0, %1, %2"
                 : "=v"(d) : "v"(voff), "s"(base) : "memory");
    return d;
}

#define WAITK(K) do { asm volatile("s_waitcnt vmcnt(%0)" :: "i"(K) : "memory"); \
                      __builtin_amdgcn_sched_barrier(0); } while (0)

#define LOADPL(I, p) do { \
    sp[(p)&3] = asm_load4(spU[I], spvo[I] + (p)*4096u); \
    Bn[(p)&3] = asm_load4(BvU[I], bcvo + (p)*4096u); \
    Cn[(p)&3] = asm_load4(CvU[I], bcvo + (p)*4096u); } while (0)

#define COMPUTE(I, n) do { \
    const f32x4 own = sp[(n)&3]; \
    const float nbR = __shfl(own.x, laneR, 64); \
    const float nbL = __shfl(own.w, laneL, 64); \
    const int rx = rxo[I]; \
    f32x4 s; \
    if (rx == 0)      { s = own; } \
    else if (rx == 1) { s.x = own.y; s.y = own.z; s.z = own.w; s.w = nbR; } \
    else              { s.x = nbL; s.y = own.x; s.z = own.y; s.w = own.z; } \
    const float anr = an_[(n)]; \
    f32x4 ab; \
    ab.x = __expf(dl.x*anr); ab.y = __expf(dl.y*anr); \
    ab.z = __expf(dl.z*anr); ab.w = __expf(dl.w*anr); \
    const f32x4 snv = ab*s + du*Bn[(n)&3]; \
    __builtin_nontemporal_store(snv, (f32x4*)(snU[I] + p0 + (n)*HW)); \
    y += snv * Cn[(n)&3]; } while (0)

#define RUN_TILE(FIRSTB, LASTB, I, IN) do { \
    LOADPL(I,3);  WAITK((FIRSTB)?9:13); \
    dl = pend_dl; du = dl * pend_uu; y = pend_uu * dpd; \
    COMPUTE(I,0); \
    LOADPL(I,4);  WAITK((FIRSTB)?10:13); COMPUTE(I,1); \
    LOADPL(I,5);  WAITK((FIRSTB)?11:13); COMPUTE(I,2); \
    LOADPL(I,6);  WAITK(12); COMPUTE(I,3); \
    LOADPL(I,7);  WAITK(12); COMPUTE(I,4); \
    LOADPL(I,8);  WAITK(12); COMPUTE(I,5); \
    LOADPL(I,9);  WAITK(12); COMPUTE(I,6); \
    LOADPL(I,10); WAITK(12); COMPUTE(I,7); \
    LOADPL(I,11); WAITK(12); COMPUTE(I,8); \
    LOADPL(I,12); WAITK(12); COMPUTE(I,9); \
    LOADPL(I,13); WAITK(12); COMPUTE(I,10); \
    LOADPL(I,14); WAITK(12); COMPUTE(I,11); \
    LOADPL(I,15); WAITK(12); COMPUTE(I,12); \
    if (!(LASTB)) { pend_dl = asm_load4(dlU[IN], uvoff); \
                    pend_uu = asm_load4(uU[IN], uvoff); \
                    LOADPL(IN,0); } \
    WAITK((LASTB)?9:14); COMPUTE(I,13); \
    if (!(LASTB)) LOADPL(IN,1); \
    WAITK((LASTB)?6:14); COMPUTE(I,14); \
    if (!(LASTB)) LOADPL(IN,2); \
    WAITK((LASTB)?3:14); COMPUTE(I,15); \
    *(f32x4*)(ynU[I] + p0) = y; \
} while (0)

__global__ __launch_bounds__(256) void main_kernel(
    const float* __restrict__ sprev, const float* __restrict__ ut,
    const float* __restrict__ delta, const float* __restrict__ Bvp,
    const float* __restrict__ Cvp, const float* __restrict__ logA,
    const float* __restrict__ Dp, const int* __restrict__ gidx,
    float* __restrict__ ynew, float* __restrict__ snew)
{
    const int k    = blockIdx.x;          // 0..767
    const int t    = threadIdx.x;
    const int p0   = t * 4;
    const int y0   = p0 >> 5;
    const int x0   = p0 & 31;
    const int lane = t & 63;
    const int laneL = (lane & ~7) | ((lane + 7) & 7);
    const int laneR = (lane & ~7) | ((lane + 1) & 7);

    const int d = k % 64;                 // invariant across tiles (768%64==0)
    const float dpd = Dp[d];
    float an_[D_STATE];
    #pragma unroll
    for (int n = 0; n < D_STATE; n++) an_[n] = -__expf(logA[d*D_STATE + n]);

    // per-tile uniforms
    const float* spU[3]; const float* BvU[3]; const float* CvU[3];
    const float* dlU[3]; const float* uU[3];
    float* snU[3]; float* ynU[3];
    unsigned spvo[3]; int rxo[3];
    bool ok = true;

    #pragma unroll
    for (int i = 0; i < 3; i++) {
        const int tau = k + GRID_MAIN*i;
        const int bv  = tau / 64;         // b*9 + v
        const int b   = bv / V;
        const int v   = bv % V;
        const size_t bvd = (size_t)tau;   // (b*9+v)*64 + d == tau
        const int gi0 = gidx[v*HW];
        const int ryo = gi0 >> 5;
        const int rx  = gi0 & 31;
        rxo[i] = rx;
        ok = ok && (rx == 0 || rx == 1 || rx == 31);
        const int ys = (y0 + ryo) & 31;
        spvo[i] = (unsigned)(((ys << 5) + x0) * 4);
        spU[i] = sprev + bvd * (D_STATE*HW);
        snU[i] = snew  + bvd * (D_STATE*HW);
        ynU[i] = ynew  + bvd * HW;
        dlU[i] = delta + ((size_t)b*D_MODEL + d)*HW;
        uU[i]  = ut    + ((size_t)b*D_MODEL + d)*HW;
        BvU[i] = Bvp + (size_t)b*D_STATE*HW;
        CvU[i] = Cvp + (size_t)b*D_STATE*HW;
    }

    const unsigned uvoff = (unsigned)p0 * 4u;
    const unsigned bcvo  = (unsigned)p0 * 4u;

    if (ok) {
        f32x4 sp[4], Bn[4], Cn[4];
        f32x4 pend_dl, pend_uu, dl, du, y;

        // block prologue: tile 0's dl, u, planes 0-2 (11 loads)
        pend_dl = asm_load4(dlU[0], uvoff);
        pend_uu = asm_load4(uU[0],  uvoff);
        LOADPL(0,0); LOADPL(0,1); LOADPL(0,2);

        RUN_TILE(1, 0, 0, 1);
        RUN_TILE(0, 0, 1, 2);
        RUN_TILE(0, 1, 2, 0);
    } else {
        // general fallback: scalar gather (not expected for V_RANGE=1)
        for (int i = 0; i < 3; i++) {
            const int tau = k + GRID_MAIN*i;
            const int v   = (tau / 64) % V;
            const int4 src4 = *(const int4*)(gidx + v*HW + p0);
            const f32x4 dl4 = *(const f32x4*)(dlU[i] + p0);
            const f32x4 uu4 = *(const f32x4*)(uU[i] + p0);
            const f32x4 du4 = dl4 * uu4;
            f32x4 yy = uu4 * dpd;
            for (int n = 0; n < D_STATE; n++) {
                const float* sp_n = spU[i] + n*HW;
                const f32x4 Bn4 = *(const f32x4*)(BvU[i] + n*HW + p0);
                const f32x4 Cn4 = *(const f32x4*)(CvU[i] + n*HW + p0);
                const float anr = an_[n];
                f32x4 s;
                s.x = sp_n[src4.x]; s.y = sp_n[src4.y];
                s.z = sp_n[src4.z]; s.w = sp_n[src4.w];
                f32x4 ab;
                ab.x = __expf(dl4.x * anr);
                ab.y = __expf(dl4.y * anr);
                ab.z = __expf(dl4.z * anr);
                ab.w = __expf(dl4.w * anr);
                const f32x4 snv = ab * s + du4 * Bn4;
                __builtin_nontemporal_store(snv, (f32x4*)(snU[i] + p0 + n*HW));
                yy += snv * Cn4;
            }
            *(f32x4*)(ynU[i] + p0) = yy;
        }
    }
}

extern "C" void kernel_launch(void* const* d_in, const int* in_sizes, int n_in,
                              void* d_out, int out_size, void* d_ws, size_t ws_size,
                              hipStream_t stream)
{
    const float* u_t       = (const float*)d_in[0];
    const float* s_prev    = (const float*)d_in[1];
    const float* gamma     = (const float*)d_in[2];
    const float* beta      = (const float*)d_in[3];
    const float* w_delta   = (const float*)d_in[4];
    const float* b_delta   = (const float*)d_in[5];
    const float* w_B       = (const float*)d_in[6];
    const float* w_C       = (const float*)d_in[7];
    const float* log_A     = (const float*)d_in[8];
    const float* D_param   = (const float*)d_in[9];
    const float* dt_sp     = (const float*)d_in[10];
    const int*   gidx      = (const int*)d_in[11];

    float* ws = (float*)d_ws;
    float* un    = ws;
    float* delta = un    + (size_t)B*D_MODEL*HW;
    float* Bv    = delta + (size_t)B*D_MODEL*HW;
    float* Cv    = Bv    + (size_t)B*D_STATE*HW;

    float* ynew = (float*)d_out;
    float* snew = ynew + (size_t)B*V*D_MODEL*HW;

    gn_kernel<<<B*GROUPS, 256, 0, stream>>>(u_t, gamma, beta, un);
    conv_kernel<<<B*96, 256, 0, stream>>>(un, w_delta, b_delta, w_B, w_C, dt_sp,
                                          delta, Bv, Cv);
    main_kernel<<<GRID_MAIN, 256, 0, stream>>>(s_prev, u_t, delta, Bv, Cv,
                                               log_A, D_param, gidx, ynew, snew);
}

// Round 12
// 102.210 us; speedup vs baseline: 1.1428x; 1.0133x over previous
//
#include <hip/hip_runtime.h>
#include <hip/hip_bf16.h>

#define D_MODEL 64
#define D_STATE 16
#define IMG     32
#define HW      (IMG*IMG)      // 1024
#define V       9
#define B       4
#define GROUPS  4
#define CPG     (D_MODEL/GROUPS) // 16

typedef float f32x4 __attribute__((ext_vector_type(4)));

// ---------------- Kernel 1: GroupNorm ----------------
__global__ __launch_bounds__(256) void gn_kernel(
    const float* __restrict__ u, const float* __restrict__ gamma,
    const float* __restrict__ beta, float* __restrict__ un)
{
    const int b = blockIdx.x / GROUPS;
    const int g = blockIdx.x % GROUPS;
    const float* base = u + ((size_t)b*D_MODEL + g*CPG) * HW;
    const int NE = CPG * HW; // 16384

    float s = 0.f, s2 = 0.f;
    for (int i = threadIdx.x; i < NE; i += 256) {
        float v = base[i];
        s += v; s2 += v*v;
    }
    for (int off = 32; off; off >>= 1) {
        s  += __shfl_down(s,  off);
        s2 += __shfl_down(s2, off);
    }
    __shared__ float red0[4], red1[4];
    const int wave = threadIdx.x >> 6;
    if ((threadIdx.x & 63) == 0) { red0[wave] = s; red1[wave] = s2; }
    __syncthreads();
    if (threadIdx.x == 0) {
        float a = 0.f, c = 0.f;
        for (int i = 0; i < 4; i++) { a += red0[i]; c += red1[i]; }
        red0[0] = a; red1[0] = c;
    }
    __syncthreads();
    const float mean = red0[0] * (1.f/16384.f);
    const float var  = red1[0] * (1.f/16384.f) - mean*mean;
    const float rstd = rsqrtf(var + 1e-5f);

    for (int i = threadIdx.x; i < NE; i += 256) {
        int c = i >> 10;
        int d = g*CPG + c;
        float v = (base[i] - mean) * rstd;
        un[((size_t)b*D_MODEL + d)*HW + (i & (HW-1))] = v*gamma[d] + beta[d];
    }
}

// ---------------- Kernel 2: circular 3x3 convs, LDS-staged, 4 co / block ----------------
__global__ __launch_bounds__(256) void conv_kernel(
    const float* __restrict__ un,
    const float* __restrict__ w_delta, const float* __restrict__ b_delta,
    const float* __restrict__ w_B, const float* __restrict__ w_C,
    const float* __restrict__ dt_sp,
    float* __restrict__ delta, float* __restrict__ Bv, float* __restrict__ Cv)
{
    const int bx    = blockIdx.x;
    const int strip = bx & 3;
    const int cog   = (bx >> 2) % 24;
    const int b     = bx / 96;
    const int co0   = cog * 4;
    const int row0  = strip * 8;

    __shared__ float xs[16][10][32];
    __shared__ float wl[4][D_MODEL*9];

    for (int i = threadIdx.x; i < 4*D_MODEL*9; i += 256) {
        const int cl = i / (D_MODEL*9);
        const int rest = i % (D_MODEL*9);
        const int co = co0 + cl;
        const float* w = (co < 64) ? (w_delta + (size_t)co*(D_MODEL*9))
                       : (co < 80) ? (w_B + (size_t)(co-64)*(D_MODEL*9))
                                   : (w_C + (size_t)(co-80)*(D_MODEL*9));
        wl[cl][rest] = w[rest];
    }

    const int ly = threadIdx.x >> 5;
    const int ox = threadIdx.x & 31;
    const int oy = row0 + ly;

    const float* x = un + (size_t)b*D_MODEL*HW;
    float a0 = 0.f, a1 = 0.f, a2 = 0.f, a3 = 0.f;

    for (int c = 0; c < 4; c++) {
        __syncthreads();
        for (int i = threadIdx.x; i < 16*10*32; i += 256) {
            const int ci = i / 320;
            const int rr = (i % 320) >> 5;
            const int xx = i & 31;
            const int gy = (row0 - 1 + rr) & 31;
            xs[ci][rr][xx] = x[(size_t)(c*16 + ci)*HW + (gy << 5) + xx];
        }
        __syncthreads();

        #pragma unroll
        for (int ci = 0; ci < 16; ci++) {
            float v[3][3];
            #pragma unroll
            for (int dy = 0; dy < 3; dy++)
                #pragma unroll
                for (int dx = 0; dx < 3; dx++)
                    v[dy][dx] = xs[ci][ly + dy][(ox + dx + 31) & 31];
            const int cig = c*16 + ci;
            const float* w0 = &wl[0][cig*9];
            const float* w1 = &wl[1][cig*9];
            const float* w2 = &wl[2][cig*9];
            const float* w3 = &wl[3][cig*9];
            #pragma unroll
            for (int t = 0; t < 9; t++) {
                const float xv = v[t/3][t%3];
                a0 = fmaf(xv, w0[t], a0);
                a1 = fmaf(xv, w1[t], a1);
                a2 = fmaf(xv, w2[t], a2);
                a3 = fmaf(xv, w3[t], a3);
            }
        }
    }

    const int p = (oy << 5) + ox;
    const float dtsp = dt_sp[0];
    float accs[4] = {a0, a1, a2, a3};
    #pragma unroll
    for (int cl = 0; cl < 4; cl++) {
        const int co = co0 + cl;
        float acc = accs[cl];
        if (co < 64) {
            acc += b_delta[co] + dtsp;
            float sp = (acc > 15.f) ? acc : log1pf(__expf(acc));
            sp = fminf(fmaxf(sp, 1e-4f), 5.f);
            delta[((size_t)b*D_MODEL + co)*HW + p] = sp;
        } else if (co < 80) {
            Bv[((size_t)b*D_STATE + (co-64))*HW + p] = acc;
        } else {
            Cv[((size_t)b*D_STATE + (co-80))*HW + p] = acc;
        }
    }
}

// ---------------- Kernel 3: main fused state update (R/W-segregated) ----------------
// grid = B*V*D_MODEL (2304) x 256 threads. Pure-read phase: 48 asm loads,
// pipelined depth 6 planes (vmcnt 18 steady, no stores in the counter);
// all 16 s_new planes held in registers; then a pure 17-store burst
// (16 KB contiguous per wave). Tests DRAM R/W-turnaround theory.
__device__ __forceinline__ f32x4 asm_load4(const float* __restrict__ base, unsigned voff) {
    f32x4 d;
    asm volatile("global_load_dwordx4 %0, %1, %2"
                 : "=v"(d) : "v"(voff), "s"(base) : "memory");
    return d;
}

#define WAITK(K) do { asm volatile("s_waitcnt vmcnt(%0)" :: "i"(K) : "memory"); \
                      __builtin_amdgcn_sched_barrier(0); } while (0)

#define LOADP(p) do { \
    spr[(p)&7] = asm_load4(sp_u, sp_voff + (p)*4096u); \
    Bnr[(p)&7] = asm_load4(Bv_u, bc_voff + (p)*4096u); \
    Cnr[(p)&7] = asm_load4(Cv_u, bc_voff + (p)*4096u); } while (0)

#define COMP(n) do { \
    const f32x4 own = spr[(n)&7]; \
    const float nbR = __shfl(own.x, laneR, 64); \
    const float nbL = __shfl(own.w, laneL, 64); \
    f32x4 s; \
    if (rxo == 0)      { s = own; } \
    else if (rxo == 1) { s.x = own.y; s.y = own.z; s.z = own.w; s.w = nbR; } \
    else               { s.x = nbL; s.y = own.x; s.z = own.y; s.w = own.z; } \
    const float anr = an_[(n)]; \
    f32x4 ab; \
    ab.x = __expf(dl.x*anr); ab.y = __expf(dl.y*anr); \
    ab.z = __expf(dl.z*anr); ab.w = __expf(dl.w*anr); \
    sn[(n)] = ab*s + du*Bnr[(n)&7]; \
    y += sn[(n)] * Cnr[(n)&7]; } while (0)

__global__ __launch_bounds__(256) void main_kernel(
    const float* __restrict__ sprev, const float* __restrict__ ut,
    const float* __restrict__ delta, const float* __restrict__ Bv,
    const float* __restrict__ Cv, const float* __restrict__ logA,
    const float* __restrict__ Dp, const int* __restrict__ gidx,
    float* __restrict__ ynew, float* __restrict__ snew)
{
    const int blk = blockIdx.x;
    const int d   = blk % D_MODEL;
    const int tmp = blk / D_MODEL;
    const int v   = tmp % V;
    const int b   = tmp / V;

    const int t  = threadIdx.x;
    const int p0 = t * 4;
    const int y0 = p0 >> 5;
    const int x0 = p0 & 31;

    const int gi0 = gidx[v*HW];       // src index of output point 0
    const int ryo = gi0 >> 5;         // row offset: src_y = (y + ryo) & 31
    const int rxo = gi0 & 31;         // col rotation: src_x = (x + rxo) & 31

    const int ys   = (y0 + ryo) & 31;
    const int srcv = (ys << 5) + x0;  // aligned float4 base in source row

    const int lane  = t & 63;
    const int laneL = (lane & ~7) | ((lane + 7) & 7);
    const int laneR = (lane & ~7) | ((lane + 1) & 7);

    const size_t bvd = (((size_t)b*V + v)*D_MODEL + d);
    const float* sp_u = sprev + bvd * D_STATE * HW;   // uniform base
    float* sn_p = snew + bvd * D_STATE * HW + p0;

    const float dpd = Dp[d];
    float an_[D_STATE];
    #pragma unroll
    for (int n = 0; n < D_STATE; n++) an_[n] = -__expf(logA[d*D_STATE + n]);

    const float* dl_u = delta + ((size_t)b*D_MODEL + d)*HW;
    const float* u_u  = ut    + ((size_t)b*D_MODEL + d)*HW;
    const float* Bv_u = Bv + (size_t)b*D_STATE*HW;    // uniform base
    const float* Cv_u = Cv + (size_t)b*D_STATE*HW;    // uniform base

    const unsigned sp_voff = (unsigned)srcv * 4u;
    const unsigned bc_voff = (unsigned)p0 * 4u;
    const unsigned uvoff   = (unsigned)p0 * 4u;

    if (rxo == 0 || rxo == 1 || rxo == 31) {
        f32x4 spr[8], Bnr[8], Cnr[8], sn[16];

        // prologue: dl, u, planes 0-5 (20 loads outstanding)
        f32x4 dl = asm_load4(dl_u, uvoff);
        f32x4 uu = asm_load4(u_u,  uvoff);
        LOADP(0); LOADP(1); LOADP(2); LOADP(3); LOADP(4); LOADP(5);
        WAITK(18);                        // dl, uu complete
        const f32x4 du = dl * uu;
        f32x4 y = uu * dpd;

        LOADP(6);  WAITK(18); COMP(0);
        LOADP(7);  WAITK(18); COMP(1);
        LOADP(8);  WAITK(18); COMP(2);
        LOADP(9);  WAITK(18); COMP(3);
        LOADP(10); WAITK(18); COMP(4);
        LOADP(11); WAITK(18); COMP(5);
        LOADP(12); WAITK(18); COMP(6);
        LOADP(13); WAITK(18); COMP(7);
        LOADP(14); WAITK(18); COMP(8);
        LOADP(15); WAITK(18); COMP(9);
        WAITK(15); COMP(10);
        WAITK(12); COMP(11);
        WAITK(9);  COMP(12);
        WAITK(6);  COMP(13);
        WAITK(3);  COMP(14);
        WAITK(0);  COMP(15);

        // pure write burst: 16 KB contiguous per wave + y
        #pragma unroll
        for (int n = 0; n < D_STATE; n++)
            __builtin_nontemporal_store(sn[n], (f32x4*)(sn_p + n*HW));
        *(f32x4*)(ynew + bvd * HW + p0) = y;
    } else {
        // general fallback: scalar gather (not expected for V_RANGE=1)
        const int4 src4 = *(const int4*)(gidx + v*HW + p0);
        const f32x4 dl = *(const f32x4*)(dl_u + p0);
        const f32x4 uu = *(const f32x4*)(u_u + p0);
        const f32x4 du = dl * uu;
        f32x4 y = uu * dpd;
        #pragma unroll
        for (int n = 0; n < D_STATE; n++) {
            const float* sp_n = sp_u + n*HW;
            const f32x4 Bn = *(const f32x4*)(Bv_u + n*HW + p0);
            const f32x4 Cn = *(const f32x4*)(Cv_u + n*HW + p0);
            const float anr = an_[n];
            f32x4 s;
            s.x = sp_n[src4.x]; s.y = sp_n[src4.y];
            s.z = sp_n[src4.z]; s.w = sp_n[src4.w];
            f32x4 ab;
            ab.x = __expf(dl.x * anr);
            ab.y = __expf(dl.y * anr);
            ab.z = __expf(dl.z * anr);
            ab.w = __expf(dl.w * anr);
            const f32x4 snv = ab * s + du * Bn;
            __builtin_nontemporal_store(snv, (f32x4*)(sn_p + n*HW));
            y += snv * Cn;
        }
        *(f32x4*)(ynew + bvd * HW + p0) = y;
    }
}

extern "C" void kernel_launch(void* const* d_in, const int* in_sizes, int n_in,
                              void* d_out, int out_size, void* d_ws, size_t ws_size,
                              hipStream_t stream)
{
    const float* u_t       = (const float*)d_in[0];
    const float* s_prev    = (const float*)d_in[1];
    const float* gamma     = (const float*)d_in[2];
    const float* beta      = (const float*)d_in[3];
    const float* w_delta   = (const float*)d_in[4];
    const float* b_delta   = (const float*)d_in[5];
    const float* w_B       = (const float*)d_in[6];
    const float* w_C       = (const float*)d_in[7];
    const float* log_A     = (const float*)d_in[8];
    const float* D_param   = (const float*)d_in[9];
    const float* dt_sp     = (const float*)d_in[10];
    const int*   gidx      = (const int*)d_in[11];

    float* ws = (float*)d_ws;
    float* un    = ws;
    float* delta = un    + (size_t)B*D_MODEL*HW;
    float* Bv    = delta + (size_t)B*D_MODEL*HW;
    float* Cv    = Bv    + (size_t)B*D_STATE*HW;

    float* ynew = (float*)d_out;
    float* snew = ynew + (size_t)B*V*D_MODEL*HW;

    gn_kernel<<<B*GROUPS, 256, 0, stream>>>(u_t, gamma, beta, un);
    conv_kernel<<<B*96, 256, 0, stream>>>(un, w_delta, b_delta, w_B, w_C, dt_sp,
                                          delta, Bv, Cv);
    main_kernel<<<B*V*D_MODEL, 256, 0, stream>>>(s_prev, u_t, delta, Bv, Cv,
                                                 log_A, D_param, gidx, ynew, snew);
}

// Round 13
// 89.483 us; speedup vs baseline: 1.3053x; 1.1422x over previous
//
#include <hip/hip_runtime.h>
#include <hip/hip_bf16.h>

#define D_MODEL 64
#define D_STATE 16
#define IMG     32
#define HW      (IMG*IMG)      // 1024
#define V       9
#define B       4
#define GROUPS  4
#define CPG     (D_MODEL/GROUPS) // 16

typedef float f32x4 __attribute__((ext_vector_type(4)));

// ---------------- Kernel 1: GroupNorm stats only ----------------
// grid = B*GROUPS (16) x 512 threads; writes {mean, rstd} per (b,g).
__global__ __launch_bounds__(512) void stats_kernel(
    const float* __restrict__ u, float2* __restrict__ stats)
{
    const int b = blockIdx.x / GROUPS;
    const int g = blockIdx.x % GROUPS;
    const float* base = u + ((size_t)b*D_MODEL + g*CPG) * HW;
    const int NE = CPG * HW; // 16384

    float s = 0.f, s2 = 0.f;
    for (int i = threadIdx.x; i < NE; i += 512) {
        float v = base[i];
        s += v; s2 += v*v;
    }
    for (int off = 32; off; off >>= 1) {
        s  += __shfl_down(s,  off);
        s2 += __shfl_down(s2, off);
    }
    __shared__ float red0[8], red1[8];
    const int wave = threadIdx.x >> 6;
    if ((threadIdx.x & 63) == 0) { red0[wave] = s; red1[wave] = s2; }
    __syncthreads();
    if (threadIdx.x == 0) {
        float a = 0.f, c = 0.f;
        for (int i = 0; i < 8; i++) { a += red0[i]; c += red1[i]; }
        const float mean = a * (1.f/16384.f);
        const float var  = c * (1.f/16384.f) - mean*mean;
        stats[blockIdx.x] = make_float2(mean, rsqrtf(var + 1e-5f));
    }
}

// ---------------- Kernel 2: circular 3x3 convs, normalization fused into staging ----------------
// grid = B * 24 * 4; co<64 -> delta (softplus+clip), 64..79 -> B_val, 80..95 -> C_val.
// xs staged as a[ci]*u + c[ci] (GroupNorm folded), so no un tensor exists.
__global__ __launch_bounds__(256) void conv_kernel(
    const float* __restrict__ u_t,
    const float* __restrict__ gamma, const float* __restrict__ beta,
    const float2* __restrict__ stats,
    const float* __restrict__ w_delta, const float* __restrict__ b_delta,
    const float* __restrict__ w_B, const float* __restrict__ w_C,
    const float* __restrict__ dt_sp,
    float* __restrict__ delta, float* __restrict__ Bv, float* __restrict__ Cv)
{
    const int bx    = blockIdx.x;
    const int strip = bx & 3;
    const int cog   = (bx >> 2) % 24;
    const int b     = bx / 96;
    const int co0   = cog * 4;
    const int row0  = strip * 8;

    __shared__ float xs[16][10][32];
    __shared__ float wl[4][D_MODEL*9];
    __shared__ float a_s[D_MODEL], c_s[D_MODEL];

    if (threadIdx.x < D_MODEL) {
        const int ci = threadIdx.x;
        const float2 st = stats[b*GROUPS + (ci >> 4)];
        const float aa = st.y * gamma[ci];
        a_s[ci] = aa;
        c_s[ci] = beta[ci] - st.x * aa;
    }
    for (int i = threadIdx.x; i < 4*D_MODEL*9; i += 256) {
        const int cl = i / (D_MODEL*9);
        const int rest = i % (D_MODEL*9);
        const int co = co0 + cl;
        const float* w = (co < 64) ? (w_delta + (size_t)co*(D_MODEL*9))
                       : (co < 80) ? (w_B + (size_t)(co-64)*(D_MODEL*9))
                                   : (w_C + (size_t)(co-80)*(D_MODEL*9));
        wl[cl][rest] = w[rest];
    }

    const int ly = threadIdx.x >> 5;
    const int ox = threadIdx.x & 31;
    const int oy = row0 + ly;

    const float* x = u_t + (size_t)b*D_MODEL*HW;
    float a0 = 0.f, a1 = 0.f, a2 = 0.f, a3 = 0.f;

    for (int c = 0; c < 4; c++) {
        __syncthreads();
        for (int i = threadIdx.x; i < 16*10*32; i += 256) {
            const int ci = i / 320;
            const int rr = (i % 320) >> 5;
            const int xx = i & 31;
            const int gy = (row0 - 1 + rr) & 31;
            const int cig = c*16 + ci;
            xs[ci][rr][xx] = fmaf(a_s[cig], x[(size_t)cig*HW + (gy << 5) + xx], c_s[cig]);
        }
        __syncthreads();

        #pragma unroll
        for (int ci = 0; ci < 16; ci++) {
            float v[3][3];
            #pragma unroll
            for (int dy = 0; dy < 3; dy++)
                #pragma unroll
                for (int dx = 0; dx < 3; dx++)
                    v[dy][dx] = xs[ci][ly + dy][(ox + dx + 31) & 31];
            const int cig = c*16 + ci;
            const float* w0 = &wl[0][cig*9];
            const float* w1 = &wl[1][cig*9];
            const float* w2 = &wl[2][cig*9];
            const float* w3 = &wl[3][cig*9];
            #pragma unroll
            for (int t = 0; t < 9; t++) {
                const float xv = v[t/3][t%3];
                a0 = fmaf(xv, w0[t], a0);
                a1 = fmaf(xv, w1[t], a1);
                a2 = fmaf(xv, w2[t], a2);
                a3 = fmaf(xv, w3[t], a3);
            }
        }
    }

    const int p = (oy << 5) + ox;
    const float dtsp = dt_sp[0];
    float accs[4] = {a0, a1, a2, a3};
    #pragma unroll
    for (int cl = 0; cl < 4; cl++) {
        const int co = co0 + cl;
        float acc = accs[cl];
        if (co < 64) {
            acc += b_delta[co] + dtsp;
            float sp = (acc > 15.f) ? acc : log1pf(__expf(acc));
            sp = fminf(fmaxf(sp, 1e-4f), 5.f);
            delta[((size_t)b*D_MODEL + co)*HW + p] = sp;
        } else if (co < 80) {
            Bv[((size_t)b*D_STATE + (co-64))*HW + p] = acc;
        } else {
            Cv[((size_t)b*D_STATE + (co-80))*HW + p] = acc;
        }
    }
}

// ---------------- Kernel 3: main fused state update (R/W-segregated, round-12 verified) ----------------
__device__ __forceinline__ f32x4 asm_load4(const float* __restrict__ base, unsigned voff) {
    f32x4 d;
    asm volatile("global_load_dwordx4 %0, %1, %2"
                 : "=v"(d) : "v"(voff), "s"(base) : "memory");
    return d;
}

#define WAITK(K) do { asm volatile("s_waitcnt vmcnt(%0)" :: "i"(K) : "memory"); \
                      __builtin_amdgcn_sched_barrier(0); } while (0)

#define LOADP(p) do { \
    spr[(p)&7] = asm_load4(sp_u, sp_voff + (p)*4096u); \
    Bnr[(p)&7] = asm_load4(Bv_u, bc_voff + (p)*4096u); \
    Cnr[(p)&7] = asm_load4(Cv_u, bc_voff + (p)*4096u); } while (0)

#define COMP(n) do { \
    const f32x4 own = spr[(n)&7]; \
    const float nbR = __shfl(own.x, laneR, 64); \
    const float nbL = __shfl(own.w, laneL, 64); \
    f32x4 s; \
    if (rxo == 0)      { s = own; } \
    else if (rxo == 1) { s.x = own.y; s.y = own.z; s.z = own.w; s.w = nbR; } \
    else               { s.x = nbL; s.y = own.x; s.z = own.y; s.w = own.z; } \
    const float anr = an_[(n)]; \
    f32x4 ab; \
    ab.x = __expf(dl.x*anr); ab.y = __expf(dl.y*anr); \
    ab.z = __expf(dl.z*anr); ab.w = __expf(dl.w*anr); \
    sn[(n)] = ab*s + du*Bnr[(n)&7]; \
    y += sn[(n)] * Cnr[(n)&7]; } while (0)

__global__ __launch_bounds__(256) void main_kernel(
    const float* __restrict__ sprev, const float* __restrict__ ut,
    const float* __restrict__ delta, const float* __restrict__ Bv,
    const float* __restrict__ Cv, const float* __restrict__ logA,
    const float* __restrict__ Dp, const int* __restrict__ gidx,
    float* __restrict__ ynew, float* __restrict__ snew)
{
    const int blk = blockIdx.x;
    const int d   = blk % D_MODEL;
    const int tmp = blk / D_MODEL;
    const int v   = tmp % V;
    const int b   = tmp / V;

    const int t  = threadIdx.x;
    const int p0 = t * 4;
    const int y0 = p0 >> 5;
    const int x0 = p0 & 31;

    const int gi0 = gidx[v*HW];       // src index of output point 0
    const int ryo = gi0 >> 5;         // row offset: src_y = (y + ryo) & 31
    const int rxo = gi0 & 31;         // col rotation: src_x = (x + rxo) & 31

    const int ys   = (y0 + ryo) & 31;
    const int srcv = (ys << 5) + x0;  // aligned float4 base in source row

    const int lane  = t & 63;
    const int laneL = (lane & ~7) | ((lane + 7) & 7);
    const int laneR = (lane & ~7) | ((lane + 1) & 7);

    const size_t bvd = (((size_t)b*V + v)*D_MODEL + d);
    const float* sp_u = sprev + bvd * D_STATE * HW;   // uniform base
    float* sn_p = snew + bvd * D_STATE * HW + p0;

    const float dpd = Dp[d];
    float an_[D_STATE];
    #pragma unroll
    for (int n = 0; n < D_STATE; n++) an_[n] = -__expf(logA[d*D_STATE + n]);

    const float* dl_u = delta + ((size_t)b*D_MODEL + d)*HW;
    const float* u_u  = ut    + ((size_t)b*D_MODEL + d)*HW;
    const float* Bv_u = Bv + (size_t)b*D_STATE*HW;    // uniform base
    const float* Cv_u = Cv + (size_t)b*D_STATE*HW;    // uniform base

    const unsigned sp_voff = (unsigned)srcv * 4u;
    const unsigned bc_voff = (unsigned)p0 * 4u;
    const unsigned uvoff   = (unsigned)p0 * 4u;

    if (rxo == 0 || rxo == 1 || rxo == 31) {
        f32x4 spr[8], Bnr[8], Cnr[8], sn[16];

        // prologue: dl, u, planes 0-5 (20 loads outstanding)
        f32x4 dl = asm_load4(dl_u, uvoff);
        f32x4 uu = asm_load4(u_u,  uvoff);
        LOADP(0); LOADP(1); LOADP(2); LOADP(3); LOADP(4); LOADP(5);
        WAITK(18);                        // dl, uu complete
        const f32x4 du = dl * uu;
        f32x4 y = uu * dpd;

        LOADP(6);  WAITK(18); COMP(0);
        LOADP(7);  WAITK(18); COMP(1);
        LOADP(8);  WAITK(18); COMP(2);
        LOADP(9);  WAITK(18); COMP(3);
        LOADP(10); WAITK(18); COMP(4);
        LOADP(11); WAITK(18); COMP(5);
        LOADP(12); WAITK(18); COMP(6);
        LOADP(13); WAITK(18); COMP(7);
        LOADP(14); WAITK(18); COMP(8);
        LOADP(15); WAITK(18); COMP(9);
        WAITK(15); COMP(10);
        WAITK(12); COMP(11);
        WAITK(9);  COMP(12);
        WAITK(6);  COMP(13);
        WAITK(3);  COMP(14);
        WAITK(0);  COMP(15);

        // pure write burst: 16 KB contiguous per wave + y
        #pragma unroll
        for (int n = 0; n < D_STATE; n++)
            __builtin_nontemporal_store(sn[n], (f32x4*)(sn_p + n*HW));
        *(f32x4*)(ynew + bvd * HW + p0) = y;
    } else {
        // general fallback: scalar gather (not expected for V_RANGE=1)
        const int4 src4 = *(const int4*)(gidx + v*HW + p0);
        const f32x4 dl = *(const f32x4*)(dl_u + p0);
        const f32x4 uu = *(const f32x4*)(u_u + p0);
        const f32x4 du = dl * uu;
        f32x4 y = uu * dpd;
        #pragma unroll
        for (int n = 0; n < D_STATE; n++) {
            const float* sp_n = sp_u + n*HW;
            const f32x4 Bn = *(const f32x4*)(Bv_u + n*HW + p0);
            const f32x4 Cn = *(const f32x4*)(Cv_u + n*HW + p0);
            const float anr = an_[n];
            f32x4 s;
            s.x = sp_n[src4.x]; s.y = sp_n[src4.y];
            s.z = sp_n[src4.z]; s.w = sp_n[src4.w];
            f32x4 ab;
            ab.x = __expf(dl.x * anr);
            ab.y = __expf(dl.y * anr);
            ab.z = __expf(dl.z * anr);
            ab.w = __expf(dl.w * anr);
            const f32x4 snv = ab * s + du * Bn;
            __builtin_nontemporal_store(snv, (f32x4*)(sn_p + n*HW));
            y += snv * Cn;
        }
        *(f32x4*)(ynew + bvd * HW + p0) = y;
    }
}

extern "C" void kernel_launch(void* const* d_in, const int* in_sizes, int n_in,
                              void* d_out, int out_size, void* d_ws, size_t ws_size,
                              hipStream_t stream)
{
    const float* u_t       = (const float*)d_in[0];
    const float* s_prev    = (const float*)d_in[1];
    const float* gamma     = (const float*)d_in[2];
    const float* beta      = (const float*)d_in[3];
    const float* w_delta   = (const float*)d_in[4];
    const float* b_delta   = (const float*)d_in[5];
    const float* w_B       = (const float*)d_in[6];
    const float* w_C       = (const float*)d_in[7];
    const float* log_A     = (const float*)d_in[8];
    const float* D_param   = (const float*)d_in[9];
    const float* dt_sp     = (const float*)d_in[10];
    const int*   gidx      = (const int*)d_in[11];

    // workspace layout (floats): delta | Bv | Cv | stats(float2 x 16)
    float* ws = (float*)d_ws;
    float*  delta = ws;                                   // 262144
    float*  Bv    = delta + (size_t)B*D_MODEL*HW;         // 65536
    float*  Cv    = Bv    + (size_t)B*D_STATE*HW;         // 65536
    float2* stats = (float2*)(Cv + (size_t)B*D_STATE*HW); // 16 float2 (8B-aligned)

    float* ynew = (float*)d_out;
    float* snew = ynew + (size_t)B*V*D_MODEL*HW;

    stats_kernel<<<B*GROUPS, 512, 0, stream>>>(u_t, stats);
    conv_kernel<<<B*96, 256, 0, stream>>>(u_t, gamma, beta, stats,
                                          w_delta, b_delta, w_B, w_C, dt_sp,
                                          delta, Bv, Cv);
    main_kernel<<<B*V*D_MODEL, 256, 0, stream>>>(s_prev, u_t, delta, Bv, Cv,
                                                 log_A, D_param, gidx, ynew, snew);
}